// Round 8
// baseline (361.690 us; speedup 1.0000x reference)
//
#include <hip/hip_runtime.h>
#include <hip/hip_bf16.h>

#define N_ 100000
#define E_ 1600000
#define D_ 128
#define H_ 4
#define C_ 32
#define XSTR 136     // padded LDS row stride (shorts): 272 B
#define NSCAT 128    // scatter/histo chunks (blocks)
#define E_CHUNK 12500 // E_/NSCAT exactly
#define PARTS 782    // ceil(N/128) partitions of 128 nodes
#define NP 128       // nodes per partition
#define EBUF 2560    // partition edge cap: mean 2046, +11 sigma
#define NLIN 640     // linear-role blocks in k_scatter_linear

using bf16 = __hip_bfloat16;
typedef __attribute__((ext_vector_type(8))) short short8;
typedef __attribute__((ext_vector_type(4))) float f32x4;
typedef __attribute__((ext_vector_type(2))) float f32x2;

__device__ __forceinline__ float u2f(unsigned u) { return __uint_as_float(u); }
__device__ __forceinline__ unsigned short f2bu(float v) {
  bf16 t = __float2bfloat16(v);
  return *(unsigned short*)&t;
}

// ---------------------------------------------------------------------------
// K1: per-(block,partition) histogram. LDS atomics only; no global atomics.
// ---------------------------------------------------------------------------
__global__ __launch_bounds__(256) void k_histo(const int* __restrict__ ei,
                                               int* __restrict__ count) {
  __shared__ int hist[PARTS];
  const int b = blockIdx.x, tid = threadIdx.x;
  for (int i = tid; i < PARTS; i += 256) hist[i] = 0;
  __syncthreads();
  const int base = b * E_CHUNK;
  for (int i = tid; i < E_CHUNK; i += 256) {
    const int d = ei[E_ + base + i];
    atomicAdd(&hist[d >> 7], 1);
  }
  __syncthreads();
  for (int p = tid; p < PARTS; p += 256) count[p * NSCAT + b] = hist[p];
}

// ---------------------------------------------------------------------------
// K2: exclusive scan -> base[p][b] (in place over count) + part_ptr[p].
// ---------------------------------------------------------------------------
__global__ __launch_bounds__(1024) void k_scan(int* __restrict__ count,
                                               int* __restrict__ part_ptr) {
  __shared__ int ps[1024];
  const int p = threadIdx.x;
  int sum = 0;
  if (p < PARTS)
    for (int b = 0; b < NSCAT; b++) sum += count[p * NSCAT + b];
  ps[p] = (p < PARTS) ? sum : 0;
  __syncthreads();
  for (int off = 1; off < 1024; off <<= 1) {
    const int v = (p >= off) ? ps[p - off] : 0;
    __syncthreads();
    ps[p] += v;
    __syncthreads();
  }
  if (p < PARTS) {
    const int excl = ps[p] - sum;
    part_ptr[p] = excl;
    int run = excl;
    for (int b = 0; b < NSCAT; b++) {
      const int c = count[p * NSCAT + b];
      count[p * NSCAT + b] = run;
      run += c;
    }
  }
  if (p == 0) part_ptr[PARTS] = E_;
}

// ---------------------------------------------------------------------------
// K3 (fused, role-split): 128 scatter blocks place edges at exact precomputed
// positions (LDS counters; block-exclusive ~64B runs -> line-dense writes,
// ~8 MB instead of 96 MB random). 640 linear blocks run the MFMA x@W^T
// (+attention logits) exactly as before. Scatter hides under linear.
// ---------------------------------------------------------------------------
__global__ __launch_bounds__(256) void k_scatter_linear(
    const float* __restrict__ x, const float* __restrict__ W,
    const float* __restrict__ att_src, const float* __restrict__ att_dst,
    const int* __restrict__ ei, const int* __restrict__ base,
    int* __restrict__ eout, bf16* __restrict__ h,
    float* __restrict__ a_src, float* __restrict__ a_dst) {
  __shared__ unsigned short WB[16384];      // 32 KB: B frags / scatter lbase
  __shared__ unsigned short XS[64 * XSTR];  // 17 KB, wave-private epilogue
  __shared__ float ats[128], atd[128];
  const int tid = threadIdx.x;
  const int bid = blockIdx.x;

  if (bid < NSCAT) {
    // ---- scatter role (aliases WB as its counter table; roles are disjoint)
    int* lbase = (int*)WB;
    const int b = bid;
    for (int p = tid; p < PARTS; p += 256) lbase[p] = base[p * NSCAT + b];
    __syncthreads();
    const int ebase = b * E_CHUNK;
    for (int i = tid; i < E_CHUNK; i += 256) {
      const int e = ebase + i;
      const int s = ei[e];
      const int d = ei[E_ + e];
      const int pos = atomicAdd(&lbase[d >> 7], 1);
      eout[pos] = s | ((d & 127) << 20);  // src:17b | dstlow:7b @ bit20
    }
    return;
  }

  // ---- linear role
  const int lb = bid - NSCAT;  // 0..639
  const int lane = tid & 63, w = tid >> 6;
  const int n15 = lane & 15, quad = lane >> 4;

  for (int i = tid; i < 16384; i += 256) {
    const int n = i >> 7, k = i & 127;
    const int kk = k >> 5, q = (k >> 3) & 3, j = k & 7;
    const int frag = kk * 8 + (n >> 4);
    WB[frag * 512 + q * 128 + (n & 15) * 8 + j] = f2bu(W[n * 128 + k]);
  }
  if (tid < 128) { ats[tid] = att_src[tid]; atd[tid] = att_dst[tid]; }
  __syncthreads();  // one-time publish; main loop is barrier-free

  const int nrb = (N_ + 63) / 64;  // 1563
  for (int rb = lb; rb < nrb; rb += NLIN) {
    const int row0 = rb * 64;
    const int arow = row0 + w * 16 + n15;

    short8 af[4];
#pragma unroll
    for (int kk = 0; kk < 4; kk++) {
      float4 p = make_float4(0.f, 0.f, 0.f, 0.f);
      float4 q = make_float4(0.f, 0.f, 0.f, 0.f);
      if (arow < N_) {
        const float* xp = &x[(size_t)arow * 128 + kk * 32 + quad * 8];
        p = *(const float4*)xp;
        q = *(const float4*)(xp + 4);
      }
      short8 a;
      a[0] = f2bu(p.x); a[1] = f2bu(p.y); a[2] = f2bu(p.z); a[3] = f2bu(p.w);
      a[4] = f2bu(q.x); a[5] = f2bu(q.y); a[6] = f2bu(q.z); a[7] = f2bu(q.w);
      af[kk] = a;
    }

    f32x4 acc[8] = {};
#pragma unroll
    for (int kk = 0; kk < 4; kk++)
#pragma unroll
      for (int t = 0; t < 8; t++) {
        const short8 bfr = *(const short8*)&WB[(kk * 8 + t) * 512 + lane * 8];
        acc[t] = __builtin_amdgcn_mfma_f32_16x16x32_bf16(af[kk], bfr, acc[t], 0, 0, 0);
      }

    // wave-private transpose: wave w owns XS rows w*16 .. w*16+15
#pragma unroll
    for (int t = 0; t < 8; t++)
#pragma unroll
      for (int reg = 0; reg < 4; reg++)
        XS[(w * 16 + quad * 4 + reg) * XSTR + t * 16 + n15] = f2bu(acc[t][reg]);

    const int lrow = lane >> 2, hd = lane & 3, cb = hd * 32;
    const int grow = row0 + w * 16 + lrow;
    if (grow < N_) {
      float ps = 0.f, pd = 0.f;
#pragma unroll
      for (int g = 0; g < 4; g++) {
        const uint4 v = *(const uint4*)&XS[(w * 16 + lrow) * XSTR + cb + g * 8];
        *(uint4*)&h[(size_t)grow * 128 + cb + g * 8] = v;
        const unsigned uu[4] = {v.x, v.y, v.z, v.w};
#pragma unroll
        for (int p2 = 0; p2 < 4; p2++) {
          const float f0 = u2f(uu[p2] << 16);
          const float f1 = u2f(uu[p2] & 0xffff0000u);
          const int cc = cb + g * 8 + p2 * 2;
          ps = fmaf(f0, ats[cc], ps);  ps = fmaf(f1, ats[cc + 1], ps);
          pd = fmaf(f0, atd[cc], pd);  pd = fmaf(f1, atd[cc + 1], pd);
        }
      }
      a_src[grow * 4 + hd] = ps;
      a_dst[grow * 4 + hd] = pd;
    }
  }
}

// ---------------------------------------------------------------------------
// K4: gather, one block per partition. Coalesced read of the partition's
// packed edges, LDS counting-sort by node (128 bins), then per-wave node
// loop with the R5 inner body (src from LDS; h-row reads coalesced 256B).
// ---------------------------------------------------------------------------
__global__ __launch_bounds__(256) void k_gather(
    const int* __restrict__ part_ptr, const int* __restrict__ eout,
    const float* __restrict__ a_src, const float* __restrict__ a_dst,
    const bf16* __restrict__ h, const float* __restrict__ bias,
    const float* __restrict__ gamma, const float* __restrict__ beta,
    float* __restrict__ out) {
  __shared__ int ebuf[EBUF];
  __shared__ int lsrc[EBUF];
  __shared__ int lcnt[NP], loff[NP], lptr[NP], ls[NP];
  const int p = blockIdx.x, tid = threadIdx.x;
  const int lo = part_ptr[p];
  int ne = part_ptr[p + 1] - lo;
  if (ne > EBUF) ne = EBUF;

  for (int i = tid; i < ne; i += 256) ebuf[i] = eout[lo + i];
  for (int n = tid; n < NP; n += 256) { lcnt[n] = 0; loff[n] = 0; }
  __syncthreads();
  for (int i = tid; i < ne; i += 256) atomicAdd(&lcnt[ebuf[i] >> 20], 1);
  __syncthreads();
  if (tid < NP) ls[tid] = lcnt[tid];
  __syncthreads();
  for (int off = 1; off < NP; off <<= 1) {
    const int v = (tid < NP && tid >= off) ? ls[tid - off] : 0;
    __syncthreads();
    if (tid < NP) ls[tid] += v;
    __syncthreads();
  }
  if (tid < NP) lptr[tid] = ls[tid] - lcnt[tid];
  __syncthreads();
  for (int i = tid; i < ne; i += 256) {
    const int v = ebuf[i];
    const int n = v >> 20;
    const int off = atomicAdd(&loff[n], 1);
    lsrc[lptr[n] + off] = v & 0x1FFFF;
  }
  __syncthreads();

  const int lane = tid & 63, wid = tid >> 6;
  const int head = lane >> 4;
  const int ch = lane * 2;

  for (int nn = 0; nn < 32; nn++) {
    const int n = wid * 32 + nn;
    const int g = p * NP + n;
    if (g >= N_) break;  // wave-uniform
    const int deg = lcnt[n];
    const int p0 = lptr[n];
    const float ad = a_dst[g * 4 + head];
    float acc0 = 0.f, acc1 = 0.f, sumw = 0.f;

    int j = 0;
    for (; j + 8 <= deg; j += 8) {
      int ss[8];
#pragma unroll
      for (int k = 0; k < 8; k++) ss[k] = lsrc[p0 + j + k];
      float as[8];
#pragma unroll
      for (int k = 0; k < 8; k++) as[k] = a_src[ss[k] * 4 + head];
      unsigned hh[8];
#pragma unroll
      for (int k = 0; k < 8; k++) hh[k] = *(const unsigned*)&h[((size_t)ss[k] << 7) + ch];
#pragma unroll
      for (int k = 0; k < 8; k++) {
        float ev = as[k] + ad;
        ev = (ev > 0.f) ? ev : 0.2f * ev;
        const float wv = __expf(ev);
        sumw += wv;
        acc0 = fmaf(wv, u2f(hh[k] << 16), acc0);
        acc1 = fmaf(wv, u2f(hh[k] & 0xffff0000u), acc1);
      }
    }
    for (; j < deg; ++j) {
      const int s = lsrc[p0 + j];
      const float as = a_src[s * 4 + head];
      const unsigned hv = *(const unsigned*)&h[((size_t)s << 7) + ch];
      float ev = as + ad;
      ev = (ev > 0.f) ? ev : 0.2f * ev;
      const float wv = __expf(ev);
      sumw += wv;
      acc0 = fmaf(wv, u2f(hv << 16), acc0);
      acc1 = fmaf(wv, u2f(hv & 0xffff0000u), acc1);
    }

    const float inv = 1.0f / (sumw + 1e-16f);
    const float2 bi = *(const float2*)&bias[ch];
    const float v0 = acc0 * inv + bi.x;
    const float v1 = acc1 * inv + bi.y;
    // cos^2+sin^2 == 1 to 1 ulp -> mag = sqrt(v^2 + 1e-12)
    const float m0i = sqrtf(v0 * v0 + 1e-12f);
    const float m1i = sqrtf(v1 * v1 + 1e-12f);

    float s1r = m0i + m1i;
#pragma unroll
    for (int off = 32; off > 0; off >>= 1) s1r += __shfl_xor(s1r, off);
    const float mu = s1r * (1.0f / 128.0f);
    const float d0 = m0i - mu, d1 = m1i - mu;
    float q = d0 * d0 + d1 * d1;
#pragma unroll
    for (int off = 32; off > 0; off >>= 1) q += __shfl_xor(q, off);
    const float rstd = rsqrtf(q * (1.0f / 128.0f) + 1e-5f);
    const float2 ga = *(const float2*)&gamma[ch];
    const float2 be = *(const float2*)&beta[ch];
    const float hn0 = d0 * rstd * ga.x + be.x;
    const float hn1 = d1 * rstd * ga.y + be.y;
    const float g0 = 0.5f * hn0 * (1.0f + erff(hn0 * 0.70710678118654752f));
    const float g1 = 0.5f * hn1 * (1.0f + erff(hn1 * 0.70710678118654752f));
    f32x2 gv; gv.x = g0; gv.y = g1;
    __builtin_nontemporal_store(gv, (f32x2*)&out[(size_t)g * 128 + ch]);
  }
}

// ---------------------------------------------------------------------------
extern "C" void kernel_launch(void* const* d_in, const int* in_sizes, int n_in,
                              void* d_out, int out_size, void* d_ws, size_t ws_size,
                              hipStream_t stream) {
  const float* x       = (const float*)d_in[0];
  const int*   ei      = (const int*)d_in[1];
  const float* W       = (const float*)d_in[2];
  const float* att_src = (const float*)d_in[3];
  const float* att_dst = (const float*)d_in[4];
  const float* bias    = (const float*)d_in[5];
  const float* gamma   = (const float*)d_in[7];
  const float* beta    = (const float*)d_in[8];
  float* out = (float*)d_out;

  // workspace (~36 MB)
  bf16*  h        = (bf16*)d_ws;                       // N*128 bf16 (25.6 MB)
  float* a_src    = (float*)(h + (size_t)N_ * D_);     // N*4 f32 (1.6 MB)
  float* a_dst    = a_src + (size_t)N_ * H_;           // N*4 f32 (1.6 MB)
  int*   count    = (int*)(a_dst + (size_t)N_ * H_);   // 784*128 int (401 KB)
  int*   part_ptr = count + 784 * NSCAT;               // 784 int
  int*   eout     = part_ptr + 800;                    // E int (6.4 MB)

  k_histo<<<NSCAT, 256, 0, stream>>>(ei, count);
  k_scan<<<1, 1024, 0, stream>>>(count, part_ptr);
  k_scatter_linear<<<NSCAT + NLIN, 256, 0, stream>>>(x, W, att_src, att_dst,
                                                     ei, count, eout, h,
                                                     a_src, a_dst);
  k_gather<<<PARTS, 256, 0, stream>>>(part_ptr, eout, a_src, a_dst, h,
                                      bias, gamma, beta, out);
}

// Round 9
// 299.307 us; speedup vs baseline: 1.2084x; 1.2084x over previous
//
#include <hip/hip_runtime.h>
#include <hip/hip_bf16.h>

#define N_ 100000
#define E_ 1600000
#define D_ 128
#define H_ 4
#define C_ 32
#define XSTR 136      // padded LDS row stride (shorts): 272 B
#define NSCAT 128     // scatter/histo chunks (blocks)
#define E_CHUNK 12500 // E_/NSCAT exactly
#define PARTS 782     // ceil(N/128) partitions of 128 nodes
#define NP 128        // nodes per partition
#define EBUF 2560     // partition edge cap: mean 2046, +11 sigma
#define NLIN 640      // linear-role blocks in k_scatter_linear

using bf16 = __hip_bfloat16;
typedef __attribute__((ext_vector_type(8))) short short8;
typedef __attribute__((ext_vector_type(4))) float f32x4;
typedef __attribute__((ext_vector_type(2))) float f32x2;

__device__ __forceinline__ float u2f(unsigned u) { return __uint_as_float(u); }
__device__ __forceinline__ unsigned short f2bu(float v) {
  bf16 t = __float2bfloat16(v);
  return *(unsigned short*)&t;
}

// ---------------------------------------------------------------------------
// K1: per-(block,partition) histogram. LDS atomics only; no global atomics.
// ---------------------------------------------------------------------------
__global__ __launch_bounds__(256) void k_histo(const int* __restrict__ ei,
                                               int* __restrict__ count) {
  __shared__ int hist[PARTS];
  const int b = blockIdx.x, tid = threadIdx.x;
  for (int i = tid; i < PARTS; i += 256) hist[i] = 0;
  __syncthreads();
  const int base = b * E_CHUNK;
  for (int i = tid; i < E_CHUNK; i += 256) {
    const int d = ei[E_ + base + i];
    atomicAdd(&hist[d >> 7], 1);
  }
  __syncthreads();
  for (int p = tid; p < PARTS; p += 256) count[p * NSCAT + b] = hist[p];
}

// ---------------------------------------------------------------------------
// K2: exclusive scan -> base[p][b] (in place over count) + part_ptr[p].
// ---------------------------------------------------------------------------
__global__ __launch_bounds__(1024) void k_scan(int* __restrict__ count,
                                               int* __restrict__ part_ptr) {
  __shared__ int ps[1024];
  const int p = threadIdx.x;
  int sum = 0;
  if (p < PARTS)
    for (int b = 0; b < NSCAT; b++) sum += count[p * NSCAT + b];
  ps[p] = (p < PARTS) ? sum : 0;
  __syncthreads();
  for (int off = 1; off < 1024; off <<= 1) {
    const int v = (p >= off) ? ps[p - off] : 0;
    __syncthreads();
    ps[p] += v;
    __syncthreads();
  }
  if (p < PARTS) {
    const int excl = ps[p] - sum;
    part_ptr[p] = excl;
    int run = excl;
    for (int b = 0; b < NSCAT; b++) {
      const int c = count[p * NSCAT + b];
      count[p * NSCAT + b] = run;
      run += c;
    }
  }
  if (p == 0) part_ptr[PARTS] = E_;
}

// ---------------------------------------------------------------------------
// K3 (fused, role-split): 128 scatter blocks place edges at exact precomputed
// positions (LDS counters; block-exclusive ~64B runs -> line-dense writes).
// 640 linear blocks run the MFMA x@W^T (+attention logits).
// ---------------------------------------------------------------------------
__global__ __launch_bounds__(256) void k_scatter_linear(
    const float* __restrict__ x, const float* __restrict__ W,
    const float* __restrict__ att_src, const float* __restrict__ att_dst,
    const int* __restrict__ ei, const int* __restrict__ base,
    int* __restrict__ eout, bf16* __restrict__ h,
    float* __restrict__ a_src, float* __restrict__ a_dst) {
  __shared__ unsigned short WB[16384];      // 32 KB: B frags / scatter lbase
  __shared__ unsigned short XS[64 * XSTR];  // 17 KB, wave-private epilogue
  __shared__ float ats[128], atd[128];
  const int tid = threadIdx.x;
  const int bid = blockIdx.x;

  if (bid < NSCAT) {
    // ---- scatter role (aliases WB as its counter table; roles are disjoint)
    int* lbase = (int*)WB;
    const int b = bid;
    for (int p = tid; p < PARTS; p += 256) lbase[p] = base[p * NSCAT + b];
    __syncthreads();
    const int ebase = b * E_CHUNK;
    for (int i = tid; i < E_CHUNK; i += 256) {
      const int e = ebase + i;
      const int s = ei[e];
      const int d = ei[E_ + e];
      const int pos = atomicAdd(&lbase[d >> 7], 1);
      eout[pos] = s | ((d & 127) << 20);  // src:17b | dstlow:7b @ bit20
    }
    return;
  }

  // ---- linear role
  const int lb = bid - NSCAT;  // 0..639
  const int lane = tid & 63, w = tid >> 6;
  const int n15 = lane & 15, quad = lane >> 4;

  for (int i = tid; i < 16384; i += 256) {
    const int n = i >> 7, k = i & 127;
    const int kk = k >> 5, q = (k >> 3) & 3, j = k & 7;
    const int frag = kk * 8 + (n >> 4);
    WB[frag * 512 + q * 128 + (n & 15) * 8 + j] = f2bu(W[n * 128 + k]);
  }
  if (tid < 128) { ats[tid] = att_src[tid]; atd[tid] = att_dst[tid]; }
  __syncthreads();  // one-time publish; main loop is barrier-free

  const int nrb = (N_ + 63) / 64;  // 1563
  for (int rb = lb; rb < nrb; rb += NLIN) {
    const int row0 = rb * 64;
    const int arow = row0 + w * 16 + n15;

    short8 af[4];
#pragma unroll
    for (int kk = 0; kk < 4; kk++) {
      float4 p = make_float4(0.f, 0.f, 0.f, 0.f);
      float4 q = make_float4(0.f, 0.f, 0.f, 0.f);
      if (arow < N_) {
        const float* xp = &x[(size_t)arow * 128 + kk * 32 + quad * 8];
        p = *(const float4*)xp;
        q = *(const float4*)(xp + 4);
      }
      short8 a;
      a[0] = f2bu(p.x); a[1] = f2bu(p.y); a[2] = f2bu(p.z); a[3] = f2bu(p.w);
      a[4] = f2bu(q.x); a[5] = f2bu(q.y); a[6] = f2bu(q.z); a[7] = f2bu(q.w);
      af[kk] = a;
    }

    f32x4 acc[8] = {};
#pragma unroll
    for (int kk = 0; kk < 4; kk++)
#pragma unroll
      for (int t = 0; t < 8; t++) {
        const short8 bfr = *(const short8*)&WB[(kk * 8 + t) * 512 + lane * 8];
        acc[t] = __builtin_amdgcn_mfma_f32_16x16x32_bf16(af[kk], bfr, acc[t], 0, 0, 0);
      }

    // wave-private transpose: wave w owns XS rows w*16 .. w*16+15
#pragma unroll
    for (int t = 0; t < 8; t++)
#pragma unroll
      for (int reg = 0; reg < 4; reg++)
        XS[(w * 16 + quad * 4 + reg) * XSTR + t * 16 + n15] = f2bu(acc[t][reg]);

    const int lrow = lane >> 2, hd = lane & 3, cb = hd * 32;
    const int grow = row0 + w * 16 + lrow;
    if (grow < N_) {
      float ps = 0.f, pd = 0.f;
#pragma unroll
      for (int g = 0; g < 4; g++) {
        const uint4 v = *(const uint4*)&XS[(w * 16 + lrow) * XSTR + cb + g * 8];
        *(uint4*)&h[(size_t)grow * 128 + cb + g * 8] = v;
        const unsigned uu[4] = {v.x, v.y, v.z, v.w};
#pragma unroll
        for (int p2 = 0; p2 < 4; p2++) {
          const float f0 = u2f(uu[p2] << 16);
          const float f1 = u2f(uu[p2] & 0xffff0000u);
          const int cc = cb + g * 8 + p2 * 2;
          ps = fmaf(f0, ats[cc], ps);  ps = fmaf(f1, ats[cc + 1], ps);
          pd = fmaf(f0, atd[cc], pd);  pd = fmaf(f1, atd[cc + 1], pd);
        }
      }
      a_src[grow * 4 + hd] = ps;
      a_dst[grow * 4 + hd] = pd;
    }
  }
}

// ---------------------------------------------------------------------------
// K4: per-partition node-sort (R8's validated gather prologue, standalone).
// Coalesced read of the partition's packed edges, 128-bin LDS counting sort,
// coalesced write of sorted srcs + per-node (ptr, deg) to global.
// ---------------------------------------------------------------------------
__global__ __launch_bounds__(256) void k_sortpart(
    const int* __restrict__ part_ptr, const int* __restrict__ eout,
    int* __restrict__ srcsorted, int* __restrict__ nodeptr,
    int* __restrict__ degN) {
  __shared__ int ebuf[EBUF];
  __shared__ int lsrc[EBUF];
  __shared__ int lcnt[NP], loff[NP], lptr[NP], ls[NP];
  const int p = blockIdx.x, tid = threadIdx.x;
  const int lo = part_ptr[p];
  int ne = part_ptr[p + 1] - lo;
  if (ne > EBUF) ne = EBUF;

  for (int i = tid; i < ne; i += 256) ebuf[i] = eout[lo + i];
  for (int n = tid; n < NP; n += 256) { lcnt[n] = 0; loff[n] = 0; }
  __syncthreads();
  for (int i = tid; i < ne; i += 256) atomicAdd(&lcnt[ebuf[i] >> 20], 1);
  __syncthreads();
  if (tid < NP) ls[tid] = lcnt[tid];
  __syncthreads();
  for (int off = 1; off < NP; off <<= 1) {
    const int v = (tid < NP && tid >= off) ? ls[tid - off] : 0;
    __syncthreads();
    if (tid < NP) ls[tid] += v;
    __syncthreads();
  }
  if (tid < NP) lptr[tid] = ls[tid] - lcnt[tid];
  __syncthreads();
  for (int i = tid; i < ne; i += 256) {
    const int v = ebuf[i];
    const int n = v >> 20;
    const int off = atomicAdd(&loff[n], 1);
    lsrc[lptr[n] + off] = v & 0x1FFFF;
  }
  __syncthreads();
  for (int i = tid; i < ne; i += 256) srcsorted[lo + i] = lsrc[i];
  if (tid < NP) {
    const int g = p * NP + tid;
    if (g < N_) { nodeptr[g] = lo + lptr[tid]; degN[g] = lcnt[tid]; }
  }
}

// ---------------------------------------------------------------------------
// K5: gather, R5's proven shape: one wave per node, 25000 blocks, no LDS,
// 4-deep readlane batches. Src list now contiguous (1 coalesced line/node).
// ---------------------------------------------------------------------------
__global__ __launch_bounds__(256) void k_gather(
    const int* __restrict__ nodeptr, const int* __restrict__ degN,
    const int* __restrict__ srcsorted,
    const float* __restrict__ a_src, const float* __restrict__ a_dst,
    const bf16* __restrict__ h, const float* __restrict__ bias,
    const float* __restrict__ gamma, const float* __restrict__ beta,
    float* __restrict__ out) {
  const int lane = threadIdx.x & 63;
  const int d = blockIdx.x * 4 + (threadIdx.x >> 6);
  if (d >= N_) return;
  const int head = lane >> 4;
  const int ch = lane * 2;
  const int deg0 = degN[d];
  const int deg = deg0 < 64 ? deg0 : 64;
  const int ptr = nodeptr[d];
  const float ad = a_dst[d * 4 + head];

  int my_src = 0;
  if (lane < deg) my_src = srcsorted[ptr + lane];  // one coalesced line

  float acc0 = 0.f, acc1 = 0.f, sumw = 0.f;

  int j = 0;
  for (; j + 4 <= deg; j += 4) {
    const int s0 = __builtin_amdgcn_readlane(my_src, j);
    const int s1 = __builtin_amdgcn_readlane(my_src, j + 1);
    const int s2 = __builtin_amdgcn_readlane(my_src, j + 2);
    const int s3 = __builtin_amdgcn_readlane(my_src, j + 3);
    const float as0 = a_src[s0 * 4 + head];
    const float as1 = a_src[s1 * 4 + head];
    const float as2 = a_src[s2 * 4 + head];
    const float as3 = a_src[s3 * 4 + head];
    const unsigned h0 = *(const unsigned*)&h[((size_t)s0 << 7) + ch];
    const unsigned h1 = *(const unsigned*)&h[((size_t)s1 << 7) + ch];
    const unsigned h2 = *(const unsigned*)&h[((size_t)s2 << 7) + ch];
    const unsigned h3 = *(const unsigned*)&h[((size_t)s3 << 7) + ch];
    float e0 = as0 + ad; e0 = (e0 > 0.f) ? e0 : 0.2f * e0;
    float e1 = as1 + ad; e1 = (e1 > 0.f) ? e1 : 0.2f * e1;
    float e2 = as2 + ad; e2 = (e2 > 0.f) ? e2 : 0.2f * e2;
    float e3 = as3 + ad; e3 = (e3 > 0.f) ? e3 : 0.2f * e3;
    const float w0 = __expf(e0), w1 = __expf(e1);
    const float w2 = __expf(e2), w3 = __expf(e3);
    sumw += w0; sumw += w1; sumw += w2; sumw += w3;
    acc0 = fmaf(w0, u2f(h0 << 16), acc0); acc1 = fmaf(w0, u2f(h0 & 0xffff0000u), acc1);
    acc0 = fmaf(w1, u2f(h1 << 16), acc0); acc1 = fmaf(w1, u2f(h1 & 0xffff0000u), acc1);
    acc0 = fmaf(w2, u2f(h2 << 16), acc0); acc1 = fmaf(w2, u2f(h2 & 0xffff0000u), acc1);
    acc0 = fmaf(w3, u2f(h3 << 16), acc0); acc1 = fmaf(w3, u2f(h3 & 0xffff0000u), acc1);
  }
  for (; j < deg; ++j) {
    const int s = __builtin_amdgcn_readlane(my_src, j);
    const float as = a_src[s * 4 + head];
    const unsigned hv = *(const unsigned*)&h[((size_t)s << 7) + ch];
    float ev = as + ad;
    ev = (ev > 0.f) ? ev : 0.2f * ev;
    const float wv = __expf(ev);
    sumw += wv;
    acc0 = fmaf(wv, u2f(hv << 16), acc0);
    acc1 = fmaf(wv, u2f(hv & 0xffff0000u), acc1);
  }

  // sumw is already the full per-head denominator in every lane.
  const float inv = 1.0f / (sumw + 1e-16f);
  const float2 bi = *(const float2*)&bias[ch];
  const float v0 = acc0 * inv + bi.x;
  const float v1 = acc1 * inv + bi.y;
  // cos^2+sin^2 == 1 to 1 ulp -> mag = sqrt(v^2 + 1e-12)
  const float m0i = sqrtf(v0 * v0 + 1e-12f);
  const float m1i = sqrtf(v1 * v1 + 1e-12f);

  float s1r = m0i + m1i;
#pragma unroll
  for (int off = 32; off > 0; off >>= 1) s1r += __shfl_xor(s1r, off);
  const float mu = s1r * (1.0f / 128.0f);
  const float d0 = m0i - mu, d1 = m1i - mu;
  float q = d0 * d0 + d1 * d1;
#pragma unroll
  for (int off = 32; off > 0; off >>= 1) q += __shfl_xor(q, off);
  const float rstd = rsqrtf(q * (1.0f / 128.0f) + 1e-5f);
  const float2 ga = *(const float2*)&gamma[ch];
  const float2 be = *(const float2*)&beta[ch];
  const float hn0 = d0 * rstd * ga.x + be.x;
  const float hn1 = d1 * rstd * ga.y + be.y;
  const float g0 = 0.5f * hn0 * (1.0f + erff(hn0 * 0.70710678118654752f));
  const float g1 = 0.5f * hn1 * (1.0f + erff(hn1 * 0.70710678118654752f));
  f32x2 gv; gv.x = g0; gv.y = g1;
  __builtin_nontemporal_store(gv, (f32x2*)&out[(size_t)d * 128 + ch]);
}

// ---------------------------------------------------------------------------
extern "C" void kernel_launch(void* const* d_in, const int* in_sizes, int n_in,
                              void* d_out, int out_size, void* d_ws, size_t ws_size,
                              hipStream_t stream) {
  const float* x       = (const float*)d_in[0];
  const int*   ei      = (const int*)d_in[1];
  const float* W       = (const float*)d_in[2];
  const float* att_src = (const float*)d_in[3];
  const float* att_dst = (const float*)d_in[4];
  const float* bias    = (const float*)d_in[5];
  const float* gamma   = (const float*)d_in[7];
  const float* beta    = (const float*)d_in[8];
  float* out = (float*)d_out;

  // workspace (~43 MB)
  bf16*  h         = (bf16*)d_ws;                      // N*128 bf16 (25.6 MB)
  float* a_src     = (float*)(h + (size_t)N_ * D_);    // N*4 f32 (1.6 MB)
  float* a_dst     = a_src + (size_t)N_ * H_;          // N*4 f32 (1.6 MB)
  int*   count     = (int*)(a_dst + (size_t)N_ * H_);  // 784*128 int (401 KB)
  int*   part_ptr  = count + 784 * NSCAT;              // 784 int
  int*   eout      = part_ptr + 800;                   // E int (6.4 MB)
  int*   srcsorted = eout + (size_t)E_;                // E int (6.4 MB)
  int*   nodeptr   = srcsorted + (size_t)E_;           // N int (0.4 MB)
  int*   degN      = nodeptr + (size_t)N_;             // N int (0.4 MB)

  k_histo<<<NSCAT, 256, 0, stream>>>(ei, count);
  k_scan<<<1, 1024, 0, stream>>>(count, part_ptr);
  k_scatter_linear<<<NSCAT + NLIN, 256, 0, stream>>>(x, W, att_src, att_dst,
                                                     ei, count, eout, h,
                                                     a_src, a_dst);
  k_sortpart<<<PARTS, 256, 0, stream>>>(part_ptr, eout, srcsorted, nodeptr, degN);
  k_gather<<<(N_ + 3) / 4, 256, 0, stream>>>(nodeptr, degN, srcsorted, a_src,
                                             a_dst, h, bias, gamma, beta, out);
}

// Round 10
// 279.690 us; speedup vs baseline: 1.2932x; 1.0701x over previous
//
#include <hip/hip_runtime.h>
#include <hip/hip_bf16.h>

#define N_ 100000
#define E_ 1600000
#define D_ 128
#define H_ 4
#define C_ 32
#define XSTR 136      // padded LDS row stride (shorts): 272 B
#define NSCAT 256     // scatter/histo chunks
#define E_CHUNK 6250  // E_/NSCAT exactly
#define PARTS 782     // ceil(N/128) partitions of 128 nodes
#define NP 128        // nodes per partition
#define EBUF 2560     // partition edge cap: mean 2046, +11 sigma
#define NLIN 512      // linear-role blocks in k_linear_histo
#define FLAT (PARTS * NSCAT)  // 200192
#define SCB 196       // scan blocks of 1024 (196*1024 >= FLAT)

using bf16 = __hip_bfloat16;
typedef __attribute__((ext_vector_type(8))) short short8;
typedef __attribute__((ext_vector_type(4))) float f32x4;
typedef __attribute__((ext_vector_type(2))) float f32x2;

__device__ __forceinline__ float u2f(unsigned u) { return __uint_as_float(u); }
__device__ __forceinline__ unsigned short f2bu(float v) {
  bf16 t = __float2bfloat16(v);
  return *(unsigned short*)&t;
}

// ---------------------------------------------------------------------------
// K1 (fused, role-split): 512 linear blocks (MFMA x@W^T + attention logits,
// validated structure) + 256 histo blocks (LDS histogram of 6250-edge chunk
// into 782 partitions). All 768 blocks co-resident (50.4KB LDS -> 3/CU).
// ---------------------------------------------------------------------------
__global__ __launch_bounds__(256) void k_linear_histo(
    const float* __restrict__ x, const float* __restrict__ W,
    const float* __restrict__ att_src, const float* __restrict__ att_dst,
    const int* __restrict__ ei, int* __restrict__ count,
    bf16* __restrict__ h, float* __restrict__ a_src, float* __restrict__ a_dst) {
  __shared__ unsigned short WB[16384];      // 32 KB: B frags / histo table
  __shared__ unsigned short XS[64 * XSTR];  // 17 KB, wave-private epilogue
  __shared__ float ats[128], atd[128];
  const int tid = threadIdx.x;
  const int bid = blockIdx.x;

  if (bid >= NLIN) {
    // ---- histo role (aliases WB; roles disjoint)
    int* hist = (int*)WB;
    const int b = bid - NLIN;  // 0..255
    for (int i = tid; i < PARTS; i += 256) hist[i] = 0;
    __syncthreads();
    const int base = b * E_CHUNK;
    for (int i = tid; i < E_CHUNK; i += 256)
      atomicAdd(&hist[ei[E_ + base + i] >> 7], 1);
    __syncthreads();
    for (int p = tid; p < PARTS; p += 256) count[p * NSCAT + b] = hist[p];
    return;
  }

  // ---- linear role
  const int lb = bid;  // 0..511
  const int lane = tid & 63, w = tid >> 6;
  const int n15 = lane & 15, quad = lane >> 4;

  for (int i = tid; i < 16384; i += 256) {
    const int n = i >> 7, k = i & 127;
    const int kk = k >> 5, q = (k >> 3) & 3, j = k & 7;
    const int frag = kk * 8 + (n >> 4);
    WB[frag * 512 + q * 128 + (n & 15) * 8 + j] = f2bu(W[n * 128 + k]);
  }
  if (tid < 128) { ats[tid] = att_src[tid]; atd[tid] = att_dst[tid]; }
  __syncthreads();  // one-time publish; main loop is barrier-free

  const int nrb = (N_ + 63) / 64;  // 1563
  for (int rb = lb; rb < nrb; rb += NLIN) {
    const int row0 = rb * 64;
    const int arow = row0 + w * 16 + n15;

    short8 af[4];
#pragma unroll
    for (int kk = 0; kk < 4; kk++) {
      float4 p = make_float4(0.f, 0.f, 0.f, 0.f);
      float4 q = make_float4(0.f, 0.f, 0.f, 0.f);
      if (arow < N_) {
        const float* xp = &x[(size_t)arow * 128 + kk * 32 + quad * 8];
        p = *(const float4*)xp;
        q = *(const float4*)(xp + 4);
      }
      short8 a;
      a[0] = f2bu(p.x); a[1] = f2bu(p.y); a[2] = f2bu(p.z); a[3] = f2bu(p.w);
      a[4] = f2bu(q.x); a[5] = f2bu(q.y); a[6] = f2bu(q.z); a[7] = f2bu(q.w);
      af[kk] = a;
    }

    f32x4 acc[8] = {};
#pragma unroll
    for (int kk = 0; kk < 4; kk++)
#pragma unroll
      for (int t = 0; t < 8; t++) {
        const short8 bfr = *(const short8*)&WB[(kk * 8 + t) * 512 + lane * 8];
        acc[t] = __builtin_amdgcn_mfma_f32_16x16x32_bf16(af[kk], bfr, acc[t], 0, 0, 0);
      }

    // wave-private transpose: wave w owns XS rows w*16 .. w*16+15
#pragma unroll
    for (int t = 0; t < 8; t++)
#pragma unroll
      for (int reg = 0; reg < 4; reg++)
        XS[(w * 16 + quad * 4 + reg) * XSTR + t * 16 + n15] = f2bu(acc[t][reg]);

    const int lrow = lane >> 2, hd = lane & 3, cb = hd * 32;
    const int grow = row0 + w * 16 + lrow;
    if (grow < N_) {
      float ps = 0.f, pd = 0.f;
#pragma unroll
      for (int g = 0; g < 4; g++) {
        const uint4 v = *(const uint4*)&XS[(w * 16 + lrow) * XSTR + cb + g * 8];
        *(uint4*)&h[(size_t)grow * 128 + cb + g * 8] = v;
        const unsigned uu[4] = {v.x, v.y, v.z, v.w};
#pragma unroll
        for (int p2 = 0; p2 < 4; p2++) {
          const float f0 = u2f(uu[p2] << 16);
          const float f1 = u2f(uu[p2] & 0xffff0000u);
          const int cc = cb + g * 8 + p2 * 2;
          ps = fmaf(f0, ats[cc], ps);  ps = fmaf(f1, ats[cc + 1], ps);
          pd = fmaf(f0, atd[cc], pd);  pd = fmaf(f1, atd[cc + 1], pd);
        }
      }
      a_src[grow * 4 + hd] = ps;
      a_dst[grow * 4 + hd] = pd;
    }
  }
}

// ---------------------------------------------------------------------------
// K2a: block-local exclusive scan over the flattened (p-major, b-minor)
// count array, 1024 entries/block; block totals -> bsum.
// ---------------------------------------------------------------------------
__global__ __launch_bounds__(1024) void k_scanA(int* __restrict__ count,
                                                int* __restrict__ bsum) {
  __shared__ int ps[1024];
  const int g = blockIdx.x, t = threadIdx.x;
  const int idx = g * 1024 + t;
  const int v = (idx < FLAT) ? count[idx] : 0;
  ps[t] = v;
  __syncthreads();
  for (int off = 1; off < 1024; off <<= 1) {
    const int add = (t >= off) ? ps[t - off] : 0;
    __syncthreads();
    ps[t] += add;
    __syncthreads();
  }
  if (idx < FLAT) count[idx] = ps[t] - v;  // block-local exclusive
  if (t == 1023) bsum[g] = ps[t];
}

// ---------------------------------------------------------------------------
// K2b: add block offsets -> global exclusive prefix; extract part_ptr.
// ---------------------------------------------------------------------------
__global__ __launch_bounds__(1024) void k_scanB(int* __restrict__ count,
                                                const int* __restrict__ bsum,
                                                int* __restrict__ part_ptr) {
  const int g = blockIdx.x, t = threadIdx.x;
  int off = 0;
  for (int i = 0; i < g; i++) off += bsum[i];  // uniform scalar chain
  const int idx = g * 1024 + t;
  if (idx < FLAT) {
    const int val = count[idx] + off;
    count[idx] = val;
    if ((idx & (NSCAT - 1)) == 0) part_ptr[idx / NSCAT] = val;
  }
  if (g == SCB - 1 && t == 1023) part_ptr[PARTS] = E_;
}

// ---------------------------------------------------------------------------
// K3: scatter edges to exact precomputed positions (LDS counters only).
// 256 blocks; block-exclusive output runs -> line-dense writes.
// ---------------------------------------------------------------------------
__global__ __launch_bounds__(256) void k_scatter(const int* __restrict__ ei,
                                                 const int* __restrict__ base,
                                                 int* __restrict__ eout) {
  __shared__ int lbase[PARTS];
  const int b = blockIdx.x, tid = threadIdx.x;
  for (int p = tid; p < PARTS; p += 256) lbase[p] = base[p * NSCAT + b];
  __syncthreads();
  const int ebase = b * E_CHUNK;
  for (int i = tid; i < E_CHUNK; i += 256) {
    const int e = ebase + i;
    const int s = ei[e];
    const int d = ei[E_ + e];
    const int pos = atomicAdd(&lbase[d >> 7], 1);
    eout[pos] = s | ((d & 127) << 20);  // src:17b | dstlow:7b @ bit20
  }
}

// ---------------------------------------------------------------------------
// K4: per-partition counting sort + PER-EDGE WEIGHTS. Lanes work on distinct
// edges (full 64-lane efficiency for the exp/leaky), writing ew[e][h] at the
// sorted position. srcsorted aliases eout (read-all -> barrier -> write-all).
// ---------------------------------------------------------------------------
__global__ __launch_bounds__(256) void k_sortw(
    const int* __restrict__ part_ptr, int* __restrict__ eout,
    const float* __restrict__ a_src, const float* __restrict__ a_dst,
    float* __restrict__ ew, int* __restrict__ nodeptr, int* __restrict__ degN) {
  __shared__ int ebuf[EBUF];
  __shared__ int lsrc[EBUF];
  __shared__ int lcnt[NP], loff[NP], lptr[NP], ls[NP];
  const int p = blockIdx.x, tid = threadIdx.x;
  const int lo = part_ptr[p];
  int ne = part_ptr[p + 1] - lo;
  if (ne > EBUF) ne = EBUF;

  for (int i = tid; i < ne; i += 256) ebuf[i] = eout[lo + i];
  for (int n = tid; n < NP; n += 256) { lcnt[n] = 0; loff[n] = 0; }
  __syncthreads();
  for (int i = tid; i < ne; i += 256) atomicAdd(&lcnt[ebuf[i] >> 20], 1);
  __syncthreads();
  if (tid < NP) ls[tid] = lcnt[tid];
  __syncthreads();
  for (int off = 1; off < NP; off <<= 1) {
    const int v = (tid < NP && tid >= off) ? ls[tid - off] : 0;
    __syncthreads();
    if (tid < NP) ls[tid] += v;
    __syncthreads();
  }
  if (tid < NP) lptr[tid] = ls[tid] - lcnt[tid];
  __syncthreads();
  for (int i = tid; i < ne; i += 256) {
    const int v = ebuf[i];
    const int n = v >> 20;
    const int s = v & 0x1FFFF;
    const int off = atomicAdd(&loff[n], 1);
    const int pos = lptr[n] + off;
    lsrc[pos] = s;
    // per-edge, per-head weight at the sorted position (distinct work/lane)
    const int d = p * NP + n;
    const float4 asv = *(const float4*)&a_src[s * 4];
    const float4 adv = *(const float4*)&a_dst[d * 4];
    float e0 = asv.x + adv.x; e0 = (e0 > 0.f) ? e0 : 0.2f * e0;
    float e1 = asv.y + adv.y; e1 = (e1 > 0.f) ? e1 : 0.2f * e1;
    float e2 = asv.z + adv.z; e2 = (e2 > 0.f) ? e2 : 0.2f * e2;
    float e3 = asv.w + adv.w; e3 = (e3 > 0.f) ? e3 : 0.2f * e3;
    float4 wv;
    wv.x = __expf(e0); wv.y = __expf(e1); wv.z = __expf(e2); wv.w = __expf(e3);
    *(float4*)&ew[(size_t)(lo + pos) * 4] = wv;
  }
  __syncthreads();
  for (int i = tid; i < ne; i += 256) eout[lo + i] = lsrc[i];  // in-place sorted
  if (tid < NP) {
    const int g = p * NP + tid;
    if (g < N_) { nodeptr[g] = lo + lptr[tid]; degN[g] = lcnt[tid]; }
  }
}

// ---------------------------------------------------------------------------
// K5: light gather — one wave per node, no LDS, weights precomputed.
// Per 4-edge batch: 4 readlane + 4 broadcast ew loads + 4 coalesced h-rows.
// ---------------------------------------------------------------------------
__global__ __launch_bounds__(256) void k_gather(
    const int* __restrict__ nodeptr, const int* __restrict__ degN,
    const int* __restrict__ srcsorted, const float* __restrict__ ew,
    const bf16* __restrict__ h, const float* __restrict__ bias,
    const float* __restrict__ gamma, const float* __restrict__ beta,
    float* __restrict__ out) {
  const int lane = threadIdx.x & 63;
  const int d = blockIdx.x * 4 + (threadIdx.x >> 6);
  if (d >= N_) return;
  const int head = lane >> 4;
  const int ch = lane * 2;
  const int deg0 = degN[d];
  const int deg = deg0 < 64 ? deg0 : 64;
  const int ptr = nodeptr[d];
  const float* __restrict__ ewp = ew + (size_t)ptr * 4;

  int my_src = 0;
  if (lane < deg) my_src = srcsorted[ptr + lane];  // one coalesced line

  float acc0 = 0.f, acc1 = 0.f, sumw = 0.f;

  int j = 0;
  for (; j + 4 <= deg; j += 4) {
    const int s0 = __builtin_amdgcn_readlane(my_src, j);
    const int s1 = __builtin_amdgcn_readlane(my_src, j + 1);
    const int s2 = __builtin_amdgcn_readlane(my_src, j + 2);
    const int s3 = __builtin_amdgcn_readlane(my_src, j + 3);
    const float w0 = ewp[(j + 0) * 4 + head];
    const float w1 = ewp[(j + 1) * 4 + head];
    const float w2 = ewp[(j + 2) * 4 + head];
    const float w3 = ewp[(j + 3) * 4 + head];
    const unsigned h0 = *(const unsigned*)&h[((size_t)s0 << 7) + ch];
    const unsigned h1 = *(const unsigned*)&h[((size_t)s1 << 7) + ch];
    const unsigned h2 = *(const unsigned*)&h[((size_t)s2 << 7) + ch];
    const unsigned h3 = *(const unsigned*)&h[((size_t)s3 << 7) + ch];
    sumw += w0 + w1 + w2 + w3;
    acc0 = fmaf(w0, u2f(h0 << 16), acc0); acc1 = fmaf(w0, u2f(h0 & 0xffff0000u), acc1);
    acc0 = fmaf(w1, u2f(h1 << 16), acc0); acc1 = fmaf(w1, u2f(h1 & 0xffff0000u), acc1);
    acc0 = fmaf(w2, u2f(h2 << 16), acc0); acc1 = fmaf(w2, u2f(h2 & 0xffff0000u), acc1);
    acc0 = fmaf(w3, u2f(h3 << 16), acc0); acc1 = fmaf(w3, u2f(h3 & 0xffff0000u), acc1);
  }
  for (; j < deg; ++j) {
    const int s = __builtin_amdgcn_readlane(my_src, j);
    const float wv = ewp[j * 4 + head];
    const unsigned hv = *(const unsigned*)&h[((size_t)s << 7) + ch];
    sumw += wv;
    acc0 = fmaf(wv, u2f(hv << 16), acc0);
    acc1 = fmaf(wv, u2f(hv & 0xffff0000u), acc1);
  }

  const float inv = 1.0f / (sumw + 1e-16f);
  const float2 bi = *(const float2*)&bias[ch];
  const float v0 = acc0 * inv + bi.x;
  const float v1 = acc1 * inv + bi.y;
  // cos^2+sin^2 == 1 to 1 ulp -> mag = sqrt(v^2 + 1e-12)
  const float m0i = sqrtf(v0 * v0 + 1e-12f);
  const float m1i = sqrtf(v1 * v1 + 1e-12f);

  float s1r = m0i + m1i;
#pragma unroll
  for (int off = 32; off > 0; off >>= 1) s1r += __shfl_xor(s1r, off);
  const float mu = s1r * (1.0f / 128.0f);
  const float d0 = m0i - mu, d1 = m1i - mu;
  float q = d0 * d0 + d1 * d1;
#pragma unroll
  for (int off = 32; off > 0; off >>= 1) q += __shfl_xor(q, off);
  const float rstd = rsqrtf(q * (1.0f / 128.0f) + 1e-5f);
  const float2 ga = *(const float2*)&gamma[ch];
  const float2 be = *(const float2*)&beta[ch];
  const float hn0 = d0 * rstd * ga.x + be.x;
  const float hn1 = d1 * rstd * ga.y + be.y;
  const float g0 = 0.5f * hn0 * (1.0f + erff(hn0 * 0.70710678118654752f));
  const float g1 = 0.5f * hn1 * (1.0f + erff(hn1 * 0.70710678118654752f));
  f32x2 gv; gv.x = g0; gv.y = g1;
  __builtin_nontemporal_store(gv, (f32x2*)&out[(size_t)d * 128 + ch]);
}

// ---------------------------------------------------------------------------
extern "C" void kernel_launch(void* const* d_in, const int* in_sizes, int n_in,
                              void* d_out, int out_size, void* d_ws, size_t ws_size,
                              hipStream_t stream) {
  const float* x       = (const float*)d_in[0];
  const int*   ei      = (const int*)d_in[1];
  const float* W       = (const float*)d_in[2];
  const float* att_src = (const float*)d_in[3];
  const float* att_dst = (const float*)d_in[4];
  const float* bias    = (const float*)d_in[5];
  const float* gamma   = (const float*)d_in[7];
  const float* beta    = (const float*)d_in[8];
  float* out = (float*)d_out;

  // workspace (~62.5 MB)
  bf16*  h        = (bf16*)d_ws;                      // N*128 bf16 (25.6 MB)
  float* a_src    = (float*)(h + (size_t)N_ * D_);    // N*4 f32 (1.6 MB)
  float* a_dst    = a_src + (size_t)N_ * H_;          // N*4 f32 (1.6 MB)
  int*   count    = (int*)(a_dst + (size_t)N_ * H_);  // PARTS*NSCAT int (800 KB)
  int*   bsum     = count + (size_t)FLAT;             // 256 int
  int*   part_ptr = bsum + 256;                       // PARTS+1 (+pad) int
  int*   eout     = part_ptr + 800;                   // E int (6.4 MB; also srcsorted)
  float* ew       = (float*)(eout + (size_t)E_);      // E*4 f32 (25.6 MB)
  int*   nodeptr  = (int*)(ew + (size_t)E_ * 4);      // N int (0.4 MB)
  int*   degN     = nodeptr + (size_t)N_;             // N int (0.4 MB)

  k_linear_histo<<<NLIN + NSCAT, 256, 0, stream>>>(x, W, att_src, att_dst, ei,
                                                   count, h, a_src, a_dst);
  k_scanA<<<SCB, 1024, 0, stream>>>(count, bsum);
  k_scanB<<<SCB, 1024, 0, stream>>>(count, bsum, part_ptr);
  k_scatter<<<NSCAT, 256, 0, stream>>>(ei, count, eout);
  k_sortw<<<PARTS, 256, 0, stream>>>(part_ptr, eout, a_src, a_dst, ew,
                                     nodeptr, degN);
  k_gather<<<(N_ + 3) / 4, 256, 0, stream>>>(nodeptr, degN, eout, ew, h,
                                             bias, gamma, beta, out);
}